// Round 1
// baseline (480.942 us; speedup 1.0000x reference)
//
#include <hip/hip_runtime.h>
#include <stdint.h>

// Problem constants (from reference)
#define NGRAPH 1024
#define DFEAT  256     // D
#define KATOM  64      // atoms per graph
#define KBOND  128     // bonds per graph

typedef __attribute__((ext_vector_type(4))) float accv_t;     // MFMA C/D (4 fp32)
typedef __attribute__((ext_vector_type(8))) short bfrag_t;    // MFMA A/B (8 bf16)
typedef __attribute__((ext_vector_type(4))) unsigned short upk4_t;
typedef __attribute__((ext_vector_type(8))) unsigned short upk8_t;

__device__ __forceinline__ unsigned short f2bf(float f) {
    union { float f; unsigned int u; } v; v.f = f;
    unsigned int r = (v.u + 0x7FFFu + ((v.u >> 16) & 1u)) >> 16;
    return (unsigned short)r;
}
__device__ __forceinline__ float bf2f(unsigned short h) {
    union { unsigned int u; float f; } v; v.u = ((unsigned int)h) << 16;
    return v.f;
}
__device__ __forceinline__ float sigm(float x) { return 1.0f / (1.0f + __expf(-x)); }
__device__ __forceinline__ float tanh_f(float x) {
    // NaN-safe at large |x|: e=inf -> 1, e=0 -> -1
    float e = __expf(2.0f * x);
    return 1.0f - 2.0f / (e + 1.0f);
}

// ---------------------------------------------------------------------------
// Prep: Wc[set][n][k] (bf16), k<256: W_ih[n,k]+W_hh[n,k]; k>=256: W_ih[n,k].
// bsum[set][n] = b_ih[n] + b_hh[n].
// grid: 2048 blocks (set = bid>>10, n = bid&1023), 512 threads (k)
// ---------------------------------------------------------------------------
__global__ __launch_bounds__(512) void k_prep(
    const float* __restrict__ WihA, const float* __restrict__ WhhA,
    const float* __restrict__ bihA, const float* __restrict__ bhhA,
    const float* __restrict__ WihB, const float* __restrict__ WhhB,
    const float* __restrict__ bihB, const float* __restrict__ bhhB,
    unsigned short* __restrict__ Wc, float* __restrict__ bsum)
{
    int bid = blockIdx.x;
    int set = bid >> 10;
    int n   = bid & 1023;
    int k   = threadIdx.x;
    const float* Wih = set ? WihB : WihA;
    const float* Whh = set ? WhhB : WhhA;
    float w = Wih[(size_t)n * 512 + k];
    if (k < 256) w += Whh[(size_t)n * 256 + k];
    Wc[((size_t)(set << 10) + n) * 512 + k] = f2bf(w);
    if (k == 0) {
        const float* bih = set ? bihB : bihA;
        const float* bhh = set ? bhhB : bhhA;
        bsum[(set << 10) + n] = bih[n] + bhh[n];
    }
}

// ---------------------------------------------------------------------------
// LSTM gate GEMM: gates[set][m][n] = sum_k hr[set][m][k]*Wc[set][n][k] + bsum
// M=1024 (graphs), N=1024 (4D), K=512. BM=BN=128, BK=32, 4 waves (64x64 each),
// 16x16x32 bf16 MFMA. grid: 128 blocks (set = bid>>6).
// ---------------------------------------------------------------------------
__global__ __launch_bounds__(256) void k_gemm(
    const float* __restrict__ hr, const unsigned short* __restrict__ Wc,
    const float* __restrict__ bsum, float* __restrict__ gates)
{
    __shared__ unsigned short sA[128 * 40];  // +8 bf16 pad -> stride 40 (80 B, 16B-aligned)
    __shared__ unsigned short sB[128 * 40];

    int set   = blockIdx.x >> 6;
    int qq    = blockIdx.x & 63;
    int mbase = (qq >> 3) * 128;
    int nbase = (qq & 7) * 128;
    int t     = threadIdx.x;
    int lane  = t & 63;
    int w     = t >> 6;
    int wrow  = (w >> 1) * 64;
    int wcol  = (w & 1) * 64;
    int l15   = lane & 15;
    int khalf = (lane >> 4) * 8;

    const float* A           = hr + (size_t)(set << 10) * 512;
    const unsigned short* Bm = Wc + (size_t)(set << 10) * 512;

    accv_t acc[4][4];
    #pragma unroll
    for (int i = 0; i < 4; ++i)
        #pragma unroll
        for (int j = 0; j < 4; ++j)
            acc[i][j] = (accv_t){0.f, 0.f, 0.f, 0.f};

    for (int k0 = 0; k0 < 512; k0 += 32) {
        // stage A tile 128x32 (fp32 -> bf16)
        #pragma unroll
        for (int i = 0; i < 4; ++i) {
            int idx4 = t + 256 * i;          // 1024 float4 total
            int row  = idx4 >> 3;            // 8 float4 per row
            int kc   = (idx4 & 7) * 4;
            const float4 a = *(const float4*)&A[(size_t)(mbase + row) * 512 + k0 + kc];
            upk4_t u;
            u[0] = f2bf(a.x); u[1] = f2bf(a.y); u[2] = f2bf(a.z); u[3] = f2bf(a.w);
            *(upk4_t*)&sA[row * 40 + kc] = u;
        }
        // stage B tile 128x32 (bf16 direct)
        #pragma unroll
        for (int i = 0; i < 2; ++i) {
            int idx8 = t + 256 * i;          // 512 ushort8 total
            int row  = idx8 >> 2;            // 4 ushort8 per row
            int kc   = (idx8 & 3) * 8;
            upk8_t u = *(const upk8_t*)&Bm[(size_t)(nbase + row) * 512 + k0 + kc];
            *(upk8_t*)&sB[row * 40 + kc] = u;
        }
        __syncthreads();

        bfrag_t a_f[4], b_f[4];
        #pragma unroll
        for (int i = 0; i < 4; ++i)
            a_f[i] = *(const bfrag_t*)&sA[(wrow + i * 16 + l15) * 40 + khalf];
        #pragma unroll
        for (int j = 0; j < 4; ++j)
            b_f[j] = *(const bfrag_t*)&sB[(wcol + j * 16 + l15) * 40 + khalf];
        #pragma unroll
        for (int i = 0; i < 4; ++i)
            #pragma unroll
            for (int j = 0; j < 4; ++j)
                acc[i][j] = __builtin_amdgcn_mfma_f32_16x16x32_bf16(a_f[i], b_f[j], acc[i][j], 0, 0, 0);
        __syncthreads();
    }

    int r4 = (lane >> 4) * 4;
    #pragma unroll
    for (int i = 0; i < 4; ++i) {
        #pragma unroll
        for (int j = 0; j < 4; ++j) {
            int col  = nbase + wcol + j * 16 + l15;
            float bs = bsum[(set << 10) + col];
            #pragma unroll
            for (int v = 0; v < 4; ++v) {
                int row = mbase + wrow + i * 16 + r4 + v;
                gates[((size_t)(set << 10) + row) * 1024 + col] = acc[i][j][v] + bs;
            }
        }
    }
}

// ---------------------------------------------------------------------------
// Attention: per-graph block. Stage1: LSTM elementwise (gates -> h,c; iter0 =
// bias only). Stage2: e_i = x_i . q (fp32), stash x tile as bf16 in LDS.
// Stage2.5: softmax over K. Stage3: r = sum alpha_i x_i from LDS.
// grid: 2048 blocks (set = bid>>10, graph = bid&1023), 256 threads.
// ---------------------------------------------------------------------------
__global__ __launch_bounds__(256) void k_attn(
    const float* __restrict__ featA, const float* __restrict__ featB,
    const float* __restrict__ gates, const float* __restrict__ bsum,
    float* __restrict__ hr, float* __restrict__ cst, int iter)
{
    __shared__ float qv[256];
    __shared__ float av[128];
    __shared__ unsigned short tile[128 * 256];   // 64 KB (bond worst case)

    int bid = blockIdx.x;
    int set = bid >> 10;
    int b   = bid & 1023;
    int K   = set ? KBOND : KATOM;
    const float* feat = set ? featB : featA;
    int t = threadIdx.x;
    size_t sb = (size_t)(set << 10) + b;

    // ---- stage 1: LSTM elementwise, d = t ----
    {
        int d = t;
        float gi, gf, gg, go, cold;
        if (iter == 0) {
            gi = bsum[(set << 10) + d];
            gf = bsum[(set << 10) + 256 + d];
            gg = bsum[(set << 10) + 512 + d];
            go = bsum[(set << 10) + 768 + d];
            cold = 0.0f;
        } else {
            const float* g = gates + sb * 1024;
            gi = g[d]; gf = g[256 + d]; gg = g[512 + d]; go = g[768 + d];
            cold = cst[sb * 256 + d];
        }
        float cn = sigm(gf) * cold + sigm(gi) * tanh_f(gg);
        float h  = sigm(go) * tanh_f(cn);
        cst[sb * 256 + d]  = cn;
        hr[sb * 512 + d]   = h;   // q half of q_star
        qv[d] = h;
    }
    __syncthreads();

    // ---- stage 2: logits + bf16 tile stash ----
    int lane = t & 63;
    int wv   = t >> 6;
    float4 qreg = *(const float4*)&qv[lane * 4];
    int npw = K >> 2;   // nodes per wave (16 atom / 32 bond)
    const float* fbase = feat + (size_t)b * K * 256;
    for (int nIdx = 0; nIdx < npw; ++nIdx) {
        int node = wv * npw + nIdx;
        const float4 x = *(const float4*)&fbase[(size_t)node * 256 + lane * 4];
        upk4_t u;
        u[0] = f2bf(x.x); u[1] = f2bf(x.y); u[2] = f2bf(x.z); u[3] = f2bf(x.w);
        *(upk4_t*)&tile[node * 256 + lane * 4] = u;
        float p = x.x * qreg.x + x.y * qreg.y + x.z * qreg.z + x.w * qreg.w;
        #pragma unroll
        for (int off = 32; off >= 1; off >>= 1) p += __shfl_xor(p, off);
        if (lane == 0) av[node] = p;
    }
    __syncthreads();

    // ---- stage 2.5: segment softmax (wave 0) ----
    if (t < 64) {
        float e0 = (t < K) ? av[t] : -1e30f;
        float e1 = (t + 64 < K) ? av[t + 64] : -1e30f;
        float m = fmaxf(e0, e1);
        #pragma unroll
        for (int off = 32; off >= 1; off >>= 1) m = fmaxf(m, __shfl_xor(m, off));
        float x0 = (t < K) ? __expf(e0 - m) : 0.0f;
        float x1 = (t + 64 < K) ? __expf(e1 - m) : 0.0f;
        float s = x0 + x1;
        #pragma unroll
        for (int off = 32; off >= 1; off >>= 1) s += __shfl_xor(s, off);
        float inv = 1.0f / s;
        if (t < K)      av[t]      = x0 * inv;
        if (t + 64 < K) av[t + 64] = x1 * inv;
    }
    __syncthreads();

    // ---- stage 3: weighted readout r, d = t ----
    {
        int d = t;
        float r = 0.0f;
        for (int i = 0; i < K; i += 4) {
            r += av[i]     * bf2f(tile[(i)     * 256 + d]);
            r += av[i + 1] * bf2f(tile[(i + 1) * 256 + d]);
            r += av[i + 2] * bf2f(tile[(i + 2) * 256 + d]);
            r += av[i + 3] * bf2f(tile[(i + 3) * 256 + d]);
        }
        hr[sb * 512 + 256 + d] = r;   // r half of q_star
    }
}

// ---------------------------------------------------------------------------
// Final concat: out[b] = [hr_atom[b] (512) | hr_bond[b] (512) | fg[b] (128)]
// grid: 1024 blocks, 288 threads (one float4 each; 1152/4 = 288)
// ---------------------------------------------------------------------------
__global__ __launch_bounds__(288) void k_out(
    const float* __restrict__ hr, const float* __restrict__ fg,
    float* __restrict__ out)
{
    int b  = blockIdx.x;
    int c4 = threadIdx.x * 4;
    float4 v;
    if (c4 < 512)       v = *(const float4*)&hr[(size_t)b * 512 + c4];
    else if (c4 < 1024) v = *(const float4*)&hr[(size_t)(1024 + b) * 512 + (c4 - 512)];
    else                v = *(const float4*)&fg[(size_t)b * 128 + (c4 - 1024)];
    *(float4*)&out[(size_t)b * 1152 + c4] = v;
}

extern "C" void kernel_launch(void* const* d_in, const int* in_sizes, int n_in,
                              void* d_out, int out_size, void* d_ws, size_t ws_size,
                              hipStream_t stream) {
    const float* feat_atom   = (const float*)d_in[0];
    const float* feat_bond   = (const float*)d_in[2];
    const float* feat_global = (const float*)d_in[4];
    const float* WihA = (const float*)d_in[5];
    const float* WhhA = (const float*)d_in[6];
    const float* bihA = (const float*)d_in[7];
    const float* bhhA = (const float*)d_in[8];
    const float* WihB = (const float*)d_in[9];
    const float* WhhB = (const float*)d_in[10];
    const float* bihB = (const float*)d_in[11];
    const float* bhhB = (const float*)d_in[12];
    float* out = (float*)d_out;

    // workspace layout (bytes)
    char* ws = (char*)d_ws;
    unsigned short* Wc = (unsigned short*)(ws + 0);         // 2*1024*512*2  = 2,097,152
    float* bsum  = (float*)(ws + 2097152);                  // 2*1024*4      = 8,192
    float* gates = (float*)(ws + 2105344);                  // 2*1024*1024*4 = 8,388,608
    float* hr    = (float*)(ws + 10493952);                 // 2*1024*512*4  = 4,194,304
    float* cst   = (float*)(ws + 14688256);                 // 2*1024*256*4  = 2,097,152
    (void)in_sizes; (void)n_in; (void)out_size; (void)ws_size;

    k_prep<<<2048, 512, 0, stream>>>(WihA, WhhA, bihA, bhhA,
                                     WihB, WhhB, bihB, bhhB, Wc, bsum);
    // iteration 0: gates = bias only, computed inside k_attn
    k_attn<<<2048, 256, 0, stream>>>(feat_atom, feat_bond, gates, bsum, hr, cst, 0);
    for (int it = 1; it < 6; ++it) {
        k_gemm<<<128, 256, 0, stream>>>(hr, Wc, bsum, gates);
        k_attn<<<2048, 256, 0, stream>>>(feat_atom, feat_bond, gates, bsum, hr, cst, it);
    }
    k_out<<<1024, 288, 0, stream>>>(hr, feat_global, out);
}

// Round 2
// 310.146 us; speedup vs baseline: 1.5507x; 1.5507x over previous
//
#include <hip/hip_runtime.h>
#include <stdint.h>

// Problem constants (from reference)
#define NGRAPH 1024
#define DFEAT  256     // D
#define KATOM  64      // atoms per graph
#define KBOND  128     // bonds per graph

typedef __attribute__((ext_vector_type(4))) float accv_t;     // MFMA C/D (4 fp32)
typedef __attribute__((ext_vector_type(8))) short bfrag_t;    // MFMA A/B (8 bf16)
typedef __attribute__((ext_vector_type(4))) unsigned short upk4_t;
typedef __attribute__((ext_vector_type(8))) unsigned short upk8_t;

__device__ __forceinline__ unsigned short f2bf(float f) {
    union { float f; unsigned int u; } v; v.f = f;
    unsigned int r = (v.u + 0x7FFFu + ((v.u >> 16) & 1u)) >> 16;
    return (unsigned short)r;
}
__device__ __forceinline__ float sigm(float x) { return 1.0f / (1.0f + __expf(-x)); }
__device__ __forceinline__ float tanh_f(float x) {
    // NaN-safe at large |x|: e=inf -> 1, e=0 -> -1
    float e = __expf(2.0f * x);
    return 1.0f - 2.0f / (e + 1.0f);
}

// ---------------------------------------------------------------------------
// Prep: Wc[set][n][k] (bf16), k<256: W_ih[n,k]+W_hh[n,k]; k>=256: W_ih[n,k].
// bsum[set][n] = b_ih[n] + b_hh[n].
// grid: 2048 blocks (set = bid>>10, n = bid&1023), 512 threads (k)
// ---------------------------------------------------------------------------
__global__ __launch_bounds__(512) void k_prep(
    const float* __restrict__ WihA, const float* __restrict__ WhhA,
    const float* __restrict__ bihA, const float* __restrict__ bhhA,
    const float* __restrict__ WihB, const float* __restrict__ WhhB,
    const float* __restrict__ bihB, const float* __restrict__ bhhB,
    unsigned short* __restrict__ Wc, float* __restrict__ bsum)
{
    int bid = blockIdx.x;
    int set = bid >> 10;
    int n   = bid & 1023;
    int k   = threadIdx.x;
    const float* Wih = set ? WihB : WihA;
    const float* Whh = set ? WhhB : WhhA;
    float w = Wih[(size_t)n * 512 + k];
    if (k < 256) w += Whh[(size_t)n * 256 + k];
    Wc[((size_t)(set << 10) + n) * 512 + k] = f2bf(w);
    if (k == 0) {
        const float* bih = set ? bihB : bihA;
        const float* bhh = set ? bhhB : bhhA;
        bsum[(set << 10) + n] = bih[n] + bhh[n];
    }
}

// ---------------------------------------------------------------------------
// LSTM gate GEMM: gates[set][m][n] = sum_k hr[set][m][k]*Wc[set][n][k] + bsum
// M=1024 (graphs), N=1024 (4D), K=512. BM=BN=128, BK=32, 4 waves (64x64 each),
// 16x16x32 bf16 MFMA. grid: 128 blocks (set = bid>>6).
// ---------------------------------------------------------------------------
__global__ __launch_bounds__(256) void k_gemm(
    const float* __restrict__ hr, const unsigned short* __restrict__ Wc,
    const float* __restrict__ bsum, float* __restrict__ gates)
{
    __shared__ unsigned short sA[128 * 40];  // +8 bf16 pad -> stride 40 (80 B, 16B-aligned)
    __shared__ unsigned short sB[128 * 40];

    int set   = blockIdx.x >> 6;
    int qq    = blockIdx.x & 63;
    int mbase = (qq >> 3) * 128;
    int nbase = (qq & 7) * 128;
    int t     = threadIdx.x;
    int lane  = t & 63;
    int w     = t >> 6;
    int wrow  = (w >> 1) * 64;
    int wcol  = (w & 1) * 64;
    int l15   = lane & 15;
    int khalf = (lane >> 4) * 8;

    const float* A           = hr + (size_t)(set << 10) * 512;
    const unsigned short* Bm = Wc + (size_t)(set << 10) * 512;

    accv_t acc[4][4];
    #pragma unroll
    for (int i = 0; i < 4; ++i)
        #pragma unroll
        for (int j = 0; j < 4; ++j)
            acc[i][j] = (accv_t){0.f, 0.f, 0.f, 0.f};

    for (int k0 = 0; k0 < 512; k0 += 32) {
        // stage A tile 128x32 (fp32 -> bf16)
        #pragma unroll
        for (int i = 0; i < 4; ++i) {
            int idx4 = t + 256 * i;          // 1024 float4 total
            int row  = idx4 >> 3;            // 8 float4 per row
            int kc   = (idx4 & 7) * 4;
            const float4 a = *(const float4*)&A[(size_t)(mbase + row) * 512 + k0 + kc];
            upk4_t u;
            u[0] = f2bf(a.x); u[1] = f2bf(a.y); u[2] = f2bf(a.z); u[3] = f2bf(a.w);
            *(upk4_t*)&sA[row * 40 + kc] = u;
        }
        // stage B tile 128x32 (bf16 direct)
        #pragma unroll
        for (int i = 0; i < 2; ++i) {
            int idx8 = t + 256 * i;          // 512 ushort8 total
            int row  = idx8 >> 2;            // 4 ushort8 per row
            int kc   = (idx8 & 3) * 8;
            upk8_t u = *(const upk8_t*)&Bm[(size_t)(nbase + row) * 512 + k0 + kc];
            *(upk8_t*)&sB[row * 40 + kc] = u;
        }
        __syncthreads();

        bfrag_t a_f[4], b_f[4];
        #pragma unroll
        for (int i = 0; i < 4; ++i)
            a_f[i] = *(const bfrag_t*)&sA[(wrow + i * 16 + l15) * 40 + khalf];
        #pragma unroll
        for (int j = 0; j < 4; ++j)
            b_f[j] = *(const bfrag_t*)&sB[(wcol + j * 16 + l15) * 40 + khalf];
        #pragma unroll
        for (int i = 0; i < 4; ++i)
            #pragma unroll
            for (int j = 0; j < 4; ++j)
                acc[i][j] = __builtin_amdgcn_mfma_f32_16x16x32_bf16(a_f[i], b_f[j], acc[i][j], 0, 0, 0);
        __syncthreads();
    }

    int r4 = (lane >> 4) * 4;
    #pragma unroll
    for (int i = 0; i < 4; ++i) {
        #pragma unroll
        for (int j = 0; j < 4; ++j) {
            int col  = nbase + wcol + j * 16 + l15;
            float bs = bsum[(set << 10) + col];
            #pragma unroll
            for (int v = 0; v < 4; ++v) {
                int row = mbase + wrow + i * 16 + r4 + v;
                gates[((size_t)(set << 10) + row) * 1024 + col] = acc[i][j][v] + bs;
            }
        }
    }
}

// ---------------------------------------------------------------------------
// Attention (online-softmax, no feat tile in LDS):
// Stage1: LSTM elementwise (gates -> h,c; iter0 = bias only), q = h in LDS.
// Stage2: each wave streams its K/4 nodes; per node: e = x.q (full-wave
//         butterfly), then online-softmax update of per-lane (m, s, racc[4])
//         with x still in registers. feat read EXACTLY once, nothing stashed.
// Stage3: merge the 4 per-wave partials via 5 KB LDS; write r.
// grid: 2048 blocks (blocks 0..1023 = bonds (2x work, start first),
//       1024..2047 = atoms), 256 threads.
// ---------------------------------------------------------------------------
__global__ __launch_bounds__(256) void k_attn(
    const float* __restrict__ featA, const float* __restrict__ featB,
    const float* __restrict__ gates, const float* __restrict__ bsum,
    float* __restrict__ hr, float* __restrict__ cst, int iter)
{
    __shared__ float qv[256];
    __shared__ float mw[4], sw[4];
    __shared__ float racc_s[4][256];

    int bid = blockIdx.x;
    int set = (bid < 1024) ? 1 : 0;          // bonds first (better tail balance)
    int b   = bid & 1023;
    int K   = set ? KBOND : KATOM;
    const float* feat = set ? featB : featA;
    int t = threadIdx.x;
    size_t sb = (size_t)(set << 10) + b;

    // ---- stage 1: LSTM elementwise, d = t ----
    {
        int d = t;
        float gi, gf, gg, go, cold;
        if (iter == 0) {
            gi = bsum[(set << 10) + d];
            gf = bsum[(set << 10) + 256 + d];
            gg = bsum[(set << 10) + 512 + d];
            go = bsum[(set << 10) + 768 + d];
            cold = 0.0f;
        } else {
            const float* g = gates + sb * 1024;
            gi = g[d]; gf = g[256 + d]; gg = g[512 + d]; go = g[768 + d];
            cold = cst[sb * 256 + d];
        }
        float cn = sigm(gf) * cold + sigm(gi) * tanh_f(gg);
        float h  = sigm(go) * tanh_f(cn);
        cst[sb * 256 + d]  = cn;
        hr[sb * 512 + d]   = h;   // q half of q_star
        qv[d] = h;
    }
    __syncthreads();

    // ---- stage 2: online softmax + weighted accumulation ----
    int lane = t & 63;
    int wv   = t >> 6;
    float4 qreg = *(const float4*)&qv[lane * 4];
    int npw = K >> 2;   // nodes per wave (16 atom / 32 bond)
    const float* fbase = feat + ((size_t)b * K + (size_t)wv * npw) * 256;

    float m = -1e30f, s = 0.0f;
    float4 racc = make_float4(0.f, 0.f, 0.f, 0.f);
    #pragma unroll 4
    for (int nIdx = 0; nIdx < npw; ++nIdx) {
        const float4 x = *(const float4*)&fbase[(size_t)nIdx * 256 + lane * 4];
        float p = x.x * qreg.x + x.y * qreg.y + x.z * qreg.z + x.w * qreg.w;
        #pragma unroll
        for (int off = 32; off >= 1; off >>= 1) p += __shfl_xor(p, off);
        float mn = fmaxf(m, p);
        float sc = __expf(m - mn);   // rescale of old state (0 on first node)
        float w  = __expf(p - mn);
        s = s * sc + w;
        racc.x = racc.x * sc + w * x.x;
        racc.y = racc.y * sc + w * x.y;
        racc.z = racc.z * sc + w * x.z;
        racc.w = racc.w * sc + w * x.w;
        m = mn;
    }
    if (lane == 0) { mw[wv] = m; sw[wv] = s; }
    *(float4*)&racc_s[wv][lane * 4] = racc;
    __syncthreads();

    // ---- stage 3: merge 4 wave partials, d = t ----
    {
        float M = fmaxf(fmaxf(mw[0], mw[1]), fmaxf(mw[2], mw[3]));
        float S = 0.0f, r = 0.0f;
        #pragma unroll
        for (int w2 = 0; w2 < 4; ++w2) {
            float f = __expf(mw[w2] - M);
            S += sw[w2] * f;
            r += racc_s[w2][t] * f;
        }
        hr[sb * 512 + 256 + t] = r / S;   // r half of q_star
    }
}

// ---------------------------------------------------------------------------
// Final concat: out[b] = [hr_atom[b] (512) | hr_bond[b] (512) | fg[b] (128)]
// grid: 1024 blocks, 288 threads (one float4 each; 1152/4 = 288)
// ---------------------------------------------------------------------------
__global__ __launch_bounds__(288) void k_out(
    const float* __restrict__ hr, const float* __restrict__ fg,
    float* __restrict__ out)
{
    int b  = blockIdx.x;
    int c4 = threadIdx.x * 4;
    float4 v;
    if (c4 < 512)       v = *(const float4*)&hr[(size_t)b * 512 + c4];
    else if (c4 < 1024) v = *(const float4*)&hr[(size_t)(1024 + b) * 512 + (c4 - 512)];
    else                v = *(const float4*)&fg[(size_t)b * 128 + (c4 - 1024)];
    *(float4*)&out[(size_t)b * 1152 + c4] = v;
}

extern "C" void kernel_launch(void* const* d_in, const int* in_sizes, int n_in,
                              void* d_out, int out_size, void* d_ws, size_t ws_size,
                              hipStream_t stream) {
    const float* feat_atom   = (const float*)d_in[0];
    const float* feat_bond   = (const float*)d_in[2];
    const float* feat_global = (const float*)d_in[4];
    const float* WihA = (const float*)d_in[5];
    const float* WhhA = (const float*)d_in[6];
    const float* bihA = (const float*)d_in[7];
    const float* bhhA = (const float*)d_in[8];
    const float* WihB = (const float*)d_in[9];
    const float* WhhB = (const float*)d_in[10];
    const float* bihB = (const float*)d_in[11];
    const float* bhhB = (const float*)d_in[12];
    float* out = (float*)d_out;

    // workspace layout (bytes)
    char* ws = (char*)d_ws;
    unsigned short* Wc = (unsigned short*)(ws + 0);         // 2*1024*512*2  = 2,097,152
    float* bsum  = (float*)(ws + 2097152);                  // 2*1024*4      = 8,192
    float* gates = (float*)(ws + 2105344);                  // 2*1024*1024*4 = 8,388,608
    float* hr    = (float*)(ws + 10493952);                 // 2*1024*512*4  = 4,194,304
    float* cst   = (float*)(ws + 14688256);                 // 2*1024*256*4  = 2,097,152
    (void)in_sizes; (void)n_in; (void)out_size; (void)ws_size;

    k_prep<<<2048, 512, 0, stream>>>(WihA, WhhA, bihA, bhhA,
                                     WihB, WhhB, bihB, bhhB, Wc, bsum);
    // iteration 0: gates = bias only, computed inside k_attn
    k_attn<<<2048, 256, 0, stream>>>(feat_atom, feat_bond, gates, bsum, hr, cst, 0);
    for (int it = 1; it < 6; ++it) {
        k_gemm<<<128, 256, 0, stream>>>(hr, Wc, bsum, gates);
        k_attn<<<2048, 256, 0, stream>>>(feat_atom, feat_bond, gates, bsum, hr, cst, it);
    }
    k_out<<<1024, 288, 0, stream>>>(hr, feat_global, out);
}

// Round 3
// 304.604 us; speedup vs baseline: 1.5789x; 1.0182x over previous
//
#include <hip/hip_runtime.h>
#include <stdint.h>

// Problem constants (from reference)
#define NGRAPH 1024
#define DFEAT  256     // D
#define KATOM  64      // atoms per graph
#define KBOND  128     // bonds per graph

typedef __attribute__((ext_vector_type(4))) float accv_t;     // MFMA C/D (4 fp32)
typedef __attribute__((ext_vector_type(8))) short bfrag_t;    // MFMA A/B (8 bf16)
typedef __attribute__((ext_vector_type(4))) unsigned short upk4_t;
typedef __attribute__((ext_vector_type(8))) unsigned short upk8_t;

__device__ __forceinline__ unsigned short f2bf(float f) {
    union { float f; unsigned int u; } v; v.f = f;
    unsigned int r = (v.u + 0x7FFFu + ((v.u >> 16) & 1u)) >> 16;
    return (unsigned short)r;
}
__device__ __forceinline__ float sigm(float x) { return 1.0f / (1.0f + __expf(-x)); }
__device__ __forceinline__ float tanh_f(float x) {
    // NaN-safe at large |x|: e=inf -> 1, e=0 -> -1
    float e = __expf(2.0f * x);
    return 1.0f - 2.0f / (e + 1.0f);
}

// ---------------------------------------------------------------------------
// Prep: Wc[set][n][k] (bf16), k<256: W_ih[n,k]+W_hh[n,k]; k>=256: W_ih[n,k].
// bsum[set][n] = b_ih[n] + b_hh[n].
// ---------------------------------------------------------------------------
__global__ __launch_bounds__(512) void k_prep(
    const float* __restrict__ WihA, const float* __restrict__ WhhA,
    const float* __restrict__ bihA, const float* __restrict__ bhhA,
    const float* __restrict__ WihB, const float* __restrict__ WhhB,
    const float* __restrict__ bihB, const float* __restrict__ bhhB,
    unsigned short* __restrict__ Wc, float* __restrict__ bsum)
{
    int bid = blockIdx.x;
    int set = bid >> 10;
    int n   = bid & 1023;
    int k   = threadIdx.x;
    const float* Wih = set ? WihB : WihA;
    const float* Whh = set ? WhhB : WhhA;
    float w = Wih[(size_t)n * 512 + k];
    if (k < 256) w += Whh[(size_t)n * 256 + k];
    Wc[((size_t)(set << 10) + n) * 512 + k] = f2bf(w);
    if (k == 0) {
        const float* bih = set ? bihB : bihA;
        const float* bhh = set ? bhhB : bhhA;
        bsum[(set << 10) + n] = bih[n] + bhh[n];
    }
}

// ---------------------------------------------------------------------------
// LSTM gate GEMM: gates[set][m][n] = sum_k hr[set][m][k]*Wc[set][n][k] + bsum
// M=1024, N=1024, K=512. BM=BN=128, BK=32, 4 waves, 16x16x32 bf16 MFMA.
// ---------------------------------------------------------------------------
__global__ __launch_bounds__(256) void k_gemm(
    const float* __restrict__ hr, const unsigned short* __restrict__ Wc,
    const float* __restrict__ bsum, float* __restrict__ gates)
{
    __shared__ unsigned short sA[128 * 40];
    __shared__ unsigned short sB[128 * 40];

    int set   = blockIdx.x >> 6;
    int qq    = blockIdx.x & 63;
    int mbase = (qq >> 3) * 128;
    int nbase = (qq & 7) * 128;
    int t     = threadIdx.x;
    int lane  = t & 63;
    int w     = t >> 6;
    int wrow  = (w >> 1) * 64;
    int wcol  = (w & 1) * 64;
    int l15   = lane & 15;
    int khalf = (lane >> 4) * 8;

    const float* A           = hr + (size_t)(set << 10) * 512;
    const unsigned short* Bm = Wc + (size_t)(set << 10) * 512;

    accv_t acc[4][4];
    #pragma unroll
    for (int i = 0; i < 4; ++i)
        #pragma unroll
        for (int j = 0; j < 4; ++j)
            acc[i][j] = (accv_t){0.f, 0.f, 0.f, 0.f};

    for (int k0 = 0; k0 < 512; k0 += 32) {
        #pragma unroll
        for (int i = 0; i < 4; ++i) {
            int idx4 = t + 256 * i;
            int row  = idx4 >> 3;
            int kc   = (idx4 & 7) * 4;
            const float4 a = *(const float4*)&A[(size_t)(mbase + row) * 512 + k0 + kc];
            upk4_t u;
            u[0] = f2bf(a.x); u[1] = f2bf(a.y); u[2] = f2bf(a.z); u[3] = f2bf(a.w);
            *(upk4_t*)&sA[row * 40 + kc] = u;
        }
        #pragma unroll
        for (int i = 0; i < 2; ++i) {
            int idx8 = t + 256 * i;
            int row  = idx8 >> 2;
            int kc   = (idx8 & 3) * 8;
            upk8_t u = *(const upk8_t*)&Bm[(size_t)(nbase + row) * 512 + k0 + kc];
            *(upk8_t*)&sB[row * 40 + kc] = u;
        }
        __syncthreads();

        bfrag_t a_f[4], b_f[4];
        #pragma unroll
        for (int i = 0; i < 4; ++i)
            a_f[i] = *(const bfrag_t*)&sA[(wrow + i * 16 + l15) * 40 + khalf];
        #pragma unroll
        for (int j = 0; j < 4; ++j)
            b_f[j] = *(const bfrag_t*)&sB[(wcol + j * 16 + l15) * 40 + khalf];
        #pragma unroll
        for (int i = 0; i < 4; ++i)
            #pragma unroll
            for (int j = 0; j < 4; ++j)
                acc[i][j] = __builtin_amdgcn_mfma_f32_16x16x32_bf16(a_f[i], b_f[j], acc[i][j], 0, 0, 0);
        __syncthreads();
    }

    int r4 = (lane >> 4) * 4;
    #pragma unroll
    for (int i = 0; i < 4; ++i) {
        #pragma unroll
        for (int j = 0; j < 4; ++j) {
            int col  = nbase + wcol + j * 16 + l15;
            float bs = bsum[(set << 10) + col];
            #pragma unroll
            for (int v = 0; v < 4; ++v) {
                int row = mbase + wrow + i * 16 + r4 + v;
                gates[((size_t)(set << 10) + row) * 1024 + col] = acc[i][j][v] + bs;
            }
        }
    }
}

// ---------------------------------------------------------------------------
// Attention (pivot-softmax, 4 nodes/wave-step via 16-lane groups):
// Stage1: LSTM elementwise -> h,c; q=h in LDS.
// Stage2: lane = (group g, sublane s); group g of wave wv owns nodes
//         wv*npw + 4*qd + g; lane holds elems d = s*16..s*16+15.
//         Dot = 16 FMA + 4 shfl (shared by 4 nodes => 1 shfl/node).
//         w = exp(e - C), C = group's first-node logit (no serial chain).
//         racc[16] accumulates w*x in registers; feat read exactly once.
// Stage3: merge 16 partials (pivot-reconciled) via LDS; r = racc/S.
// grid: 2048 blocks (0..1023 bonds, 1024..2047 atoms), 256 threads.
// ---------------------------------------------------------------------------
__global__ __launch_bounds__(256) void k_attn(
    const float* __restrict__ featA, const float* __restrict__ featB,
    const float* __restrict__ gates, const float* __restrict__ bsum,
    float* __restrict__ hr, float* __restrict__ cst, int iter)
{
    __shared__ float qv[256];
    __shared__ float sw_s[16], cw_s[16];
    __shared__ float racc_s[16][260];   // +4 pad: conflict-free partial stores

    int bid = blockIdx.x;
    int set = (bid < 1024) ? 1 : 0;          // bonds first (2x work, tail balance)
    int b   = bid & 1023;
    int K   = set ? KBOND : KATOM;
    const float* feat = set ? featB : featA;
    int t = threadIdx.x;
    size_t sb = (size_t)(set << 10) + b;

    // ---- stage 1: LSTM elementwise, d = t ----
    {
        int d = t;
        float gi, gf, gg, go, cold;
        if (iter == 0) {
            gi = bsum[(set << 10) + d];
            gf = bsum[(set << 10) + 256 + d];
            gg = bsum[(set << 10) + 512 + d];
            go = bsum[(set << 10) + 768 + d];
            cold = 0.0f;
        } else {
            const float* g = gates + sb * 1024;
            gi = g[d]; gf = g[256 + d]; gg = g[512 + d]; go = g[768 + d];
            cold = cst[sb * 256 + d];
        }
        float cn = sigm(gf) * cold + sigm(gi) * tanh_f(gg);
        float h  = sigm(go) * tanh_f(cn);
        cst[sb * 256 + d]  = cn;
        hr[sb * 512 + d]   = h;   // q half of q_star
        qv[d] = h;
    }
    __syncthreads();

    // ---- stage 2: logits + weighted accumulation, 4 nodes per step ----
    int lane = t & 63;
    int wv   = t >> 6;
    int g    = lane >> 4;     // group 0..3 (node within quad)
    int s    = lane & 15;     // sublane: elems s*16..s*16+15

    const float* qp = &qv[s * 16];
    float4 q0 = *(const float4*)(qp);
    float4 q1 = *(const float4*)(qp + 4);
    float4 q2 = *(const float4*)(qp + 8);
    float4 q3 = *(const float4*)(qp + 12);

    int npw = K >> 2;         // nodes per wave (16 atom / 32 bond)
    int nq  = npw >> 2;       // quads per wave (4 atom / 8 bond)
    const float* fb = feat + ((size_t)b * K + (size_t)(wv * npw + g)) * 256 + s * 16;

    float C = 0.0f, sacc = 0.0f;
    float4 r0 = make_float4(0.f,0.f,0.f,0.f), r1 = r0, r2 = r0, r3 = r0;

    #pragma unroll 2
    for (int qd = 0; qd < nq; ++qd) {
        const float* p = fb + (size_t)qd * 1024;
        float4 x0 = *(const float4*)(p);
        float4 x1 = *(const float4*)(p + 4);
        float4 x2 = *(const float4*)(p + 8);
        float4 x3 = *(const float4*)(p + 12);
        float e01 = x0.x*q0.x + x0.y*q0.y + x0.z*q0.z + x0.w*q0.w
                  + x1.x*q1.x + x1.y*q1.y + x1.z*q1.z + x1.w*q1.w;
        float e23 = x2.x*q2.x + x2.y*q2.y + x2.z*q2.z + x2.w*q2.w
                  + x3.x*q3.x + x3.y*q3.y + x3.z*q3.z + x3.w*q3.w;
        float e = e01 + e23;
        e += __shfl_xor(e, 1);
        e += __shfl_xor(e, 2);
        e += __shfl_xor(e, 4);
        e += __shfl_xor(e, 8);
        float w;
        if (qd == 0) { C = e; w = 1.0f; }
        else         { w = __expf(e - C); }
        sacc += w;
        r0.x += w*x0.x; r0.y += w*x0.y; r0.z += w*x0.z; r0.w += w*x0.w;
        r1.x += w*x1.x; r1.y += w*x1.y; r1.z += w*x1.z; r1.w += w*x1.w;
        r2.x += w*x2.x; r2.y += w*x2.y; r2.z += w*x2.z; r2.w += w*x2.w;
        r3.x += w*x3.x; r3.y += w*x3.y; r3.z += w*x3.z; r3.w += w*x3.w;
    }

    int pid = (wv << 2) | g;
    *(float4*)&racc_s[pid][s * 16 + 0]  = r0;
    *(float4*)&racc_s[pid][s * 16 + 4]  = r1;
    *(float4*)&racc_s[pid][s * 16 + 8]  = r2;
    *(float4*)&racc_s[pid][s * 16 + 12] = r3;
    if (s == 0) { sw_s[pid] = sacc; cw_s[pid] = C; }
    __syncthreads();

    // ---- stage 3: pivot-reconciled merge of 16 partials, d = t ----
    {
        float Cm = cw_s[0];
        #pragma unroll
        for (int p2 = 1; p2 < 16; ++p2) Cm = fmaxf(Cm, cw_s[p2]);
        float S = 0.0f, r = 0.0f;
        #pragma unroll
        for (int p2 = 0; p2 < 16; ++p2) {
            float f = __expf(cw_s[p2] - Cm);
            S += sw_s[p2] * f;
            r += racc_s[p2][t] * f;
        }
        hr[sb * 512 + 256 + t] = r / S;   // r half of q_star
    }
}

// ---------------------------------------------------------------------------
// Final concat: out[b] = [hr_atom[b] (512) | hr_bond[b] (512) | fg[b] (128)]
// ---------------------------------------------------------------------------
__global__ __launch_bounds__(288) void k_out(
    const float* __restrict__ hr, const float* __restrict__ fg,
    float* __restrict__ out)
{
    int b  = blockIdx.x;
    int c4 = threadIdx.x * 4;
    float4 v;
    if (c4 < 512)       v = *(const float4*)&hr[(size_t)b * 512 + c4];
    else if (c4 < 1024) v = *(const float4*)&hr[(size_t)(1024 + b) * 512 + (c4 - 512)];
    else                v = *(const float4*)&fg[(size_t)b * 128 + (c4 - 1024)];
    *(float4*)&out[(size_t)b * 1152 + c4] = v;
}

extern "C" void kernel_launch(void* const* d_in, const int* in_sizes, int n_in,
                              void* d_out, int out_size, void* d_ws, size_t ws_size,
                              hipStream_t stream) {
    const float* feat_atom   = (const float*)d_in[0];
    const float* feat_bond   = (const float*)d_in[2];
    const float* feat_global = (const float*)d_in[4];
    const float* WihA = (const float*)d_in[5];
    const float* WhhA = (const float*)d_in[6];
    const float* bihA = (const float*)d_in[7];
    const float* bhhA = (const float*)d_in[8];
    const float* WihB = (const float*)d_in[9];
    const float* WhhB = (const float*)d_in[10];
    const float* bihB = (const float*)d_in[11];
    const float* bhhB = (const float*)d_in[12];
    float* out = (float*)d_out;

    // workspace layout (bytes)
    char* ws = (char*)d_ws;
    unsigned short* Wc = (unsigned short*)(ws + 0);         // 2*1024*512*2  = 2,097,152
    float* bsum  = (float*)(ws + 2097152);                  // 2*1024*4      = 8,192
    float* gates = (float*)(ws + 2105344);                  // 2*1024*1024*4 = 8,388,608
    float* hr    = (float*)(ws + 10493952);                 // 2*1024*512*4  = 4,194,304
    float* cst   = (float*)(ws + 14688256);                 // 2*1024*256*4  = 2,097,152
    (void)in_sizes; (void)n_in; (void)out_size; (void)ws_size;

    k_prep<<<2048, 512, 0, stream>>>(WihA, WhhA, bihA, bhhA,
                                     WihB, WhhB, bihB, bhhB, Wc, bsum);
    // iteration 0: gates = bias only, computed inside k_attn
    k_attn<<<2048, 256, 0, stream>>>(feat_atom, feat_bond, gates, bsum, hr, cst, 0);
    for (int it = 1; it < 6; ++it) {
        k_gemm<<<128, 256, 0, stream>>>(hr, Wc, bsum, gates);
        k_attn<<<2048, 256, 0, stream>>>(feat_atom, feat_bond, gates, bsum, hr, cst, it);
    }
    k_out<<<1024, 288, 0, stream>>>(hr, feat_global, out);
}

// Round 4
// 268.604 us; speedup vs baseline: 1.7905x; 1.1340x over previous
//
#include <hip/hip_runtime.h>
#include <stdint.h>

// Problem constants (from reference)
#define NGRAPH 1024
#define DFEAT  256     // D
#define KATOM  64      // atoms per graph
#define KBOND  128     // bonds per graph

typedef __attribute__((ext_vector_type(4))) float accv_t;     // MFMA C/D (4 fp32)
typedef __attribute__((ext_vector_type(8))) short bfrag_t;    // MFMA A/B (8 bf16)
typedef __attribute__((ext_vector_type(4))) unsigned short upk4_t;
typedef __attribute__((ext_vector_type(8))) unsigned short upk8_t;

__device__ __forceinline__ unsigned short f2bf(float f) {
    union { float f; unsigned int u; } v; v.f = f;
    unsigned int r = (v.u + 0x7FFFu + ((v.u >> 16) & 1u)) >> 16;
    return (unsigned short)r;
}
__device__ __forceinline__ float bf2f(unsigned short h) {
    union { unsigned int u; float f; } v; v.u = ((unsigned int)h) << 16;
    return v.f;
}
__device__ __forceinline__ float sigm(float x) { return 1.0f / (1.0f + __expf(-x)); }
__device__ __forceinline__ float tanh_f(float x) {
    float e = __expf(2.0f * x);
    return 1.0f - 2.0f / (e + 1.0f);
}

// ---------------------------------------------------------------------------
// Prep: Wc[set][n][k] (bf16), k<256: W_ih[n,k]+W_hh[n,k]; k>=256: W_ih[n,k].
// ---------------------------------------------------------------------------
__global__ __launch_bounds__(512) void k_prep(
    const float* __restrict__ WihA, const float* __restrict__ WhhA,
    const float* __restrict__ bihA, const float* __restrict__ bhhA,
    const float* __restrict__ WihB, const float* __restrict__ WhhB,
    const float* __restrict__ bihB, const float* __restrict__ bhhB,
    unsigned short* __restrict__ Wc, float* __restrict__ bsum)
{
    int bid = blockIdx.x;
    int set = bid >> 10;
    int n   = bid & 1023;
    int k   = threadIdx.x;
    const float* Wih = set ? WihB : WihA;
    const float* Whh = set ? WhhB : WhhA;
    float w = Wih[(size_t)n * 512 + k];
    if (k < 256) w += Whh[(size_t)n * 256 + k];
    Wc[((size_t)(set << 10) + n) * 512 + k] = f2bf(w);
    if (k == 0) {
        const float* bih = set ? bihB : bihA;
        const float* bhh = set ? bhhB : bhhA;
        bsum[(set << 10) + n] = bih[n] + bhh[n];
    }
}

// ---------------------------------------------------------------------------
// LSTM gate GEMM (unchanged): M=1024, N=1024, K=512, bf16 MFMA.
// ---------------------------------------------------------------------------
__global__ __launch_bounds__(256) void k_gemm(
    const float* __restrict__ hr, const unsigned short* __restrict__ Wc,
    const float* __restrict__ bsum, float* __restrict__ gates)
{
    __shared__ unsigned short sA[128 * 40];
    __shared__ unsigned short sB[128 * 40];

    int set   = blockIdx.x >> 6;
    int qq    = blockIdx.x & 63;
    int mbase = (qq >> 3) * 128;
    int nbase = (qq & 7) * 128;
    int t     = threadIdx.x;
    int lane  = t & 63;
    int w     = t >> 6;
    int wrow  = (w >> 1) * 64;
    int wcol  = (w & 1) * 64;
    int l15   = lane & 15;
    int khalf = (lane >> 4) * 8;

    const float* A           = hr + (size_t)(set << 10) * 512;
    const unsigned short* Bm = Wc + (size_t)(set << 10) * 512;

    accv_t acc[4][4];
    #pragma unroll
    for (int i = 0; i < 4; ++i)
        #pragma unroll
        for (int j = 0; j < 4; ++j)
            acc[i][j] = (accv_t){0.f, 0.f, 0.f, 0.f};

    for (int k0 = 0; k0 < 512; k0 += 32) {
        #pragma unroll
        for (int i = 0; i < 4; ++i) {
            int idx4 = t + 256 * i;
            int row  = idx4 >> 3;
            int kc   = (idx4 & 7) * 4;
            const float4 a = *(const float4*)&A[(size_t)(mbase + row) * 512 + k0 + kc];
            upk4_t u;
            u[0] = f2bf(a.x); u[1] = f2bf(a.y); u[2] = f2bf(a.z); u[3] = f2bf(a.w);
            *(upk4_t*)&sA[row * 40 + kc] = u;
        }
        #pragma unroll
        for (int i = 0; i < 2; ++i) {
            int idx8 = t + 256 * i;
            int row  = idx8 >> 2;
            int kc   = (idx8 & 3) * 8;
            upk8_t u = *(const upk8_t*)&Bm[(size_t)(nbase + row) * 512 + k0 + kc];
            *(upk8_t*)&sB[row * 40 + kc] = u;
        }
        __syncthreads();

        bfrag_t a_f[4], b_f[4];
        #pragma unroll
        for (int i = 0; i < 4; ++i)
            a_f[i] = *(const bfrag_t*)&sA[(wrow + i * 16 + l15) * 40 + khalf];
        #pragma unroll
        for (int j = 0; j < 4; ++j)
            b_f[j] = *(const bfrag_t*)&sB[(wcol + j * 16 + l15) * 40 + khalf];
        #pragma unroll
        for (int i = 0; i < 4; ++i)
            #pragma unroll
            for (int j = 0; j < 4; ++j)
                acc[i][j] = __builtin_amdgcn_mfma_f32_16x16x32_bf16(a_f[i], b_f[j], acc[i][j], 0, 0, 0);
        __syncthreads();
    }

    int r4 = (lane >> 4) * 4;
    #pragma unroll
    for (int i = 0; i < 4; ++i) {
        #pragma unroll
        for (int j = 0; j < 4; ++j) {
            int col  = nbase + wcol + j * 16 + l15;
            float bs = bsum[(set << 10) + col];
            #pragma unroll
            for (int v = 0; v < 4; ++v) {
                int row = mbase + wrow + i * 16 + r4 + v;
                gates[((size_t)(set << 10) + row) * 1024 + col] = acc[i][j][v] + bs;
            }
        }
    }
}

// ---------------------------------------------------------------------------
// Attention, templated on MODE:
//  MODE 0: read fp32 feat (chunk-contiguous), write bf16 copy, iter==0
//  MODE 1: read bf16 copy (chunk-contiguous), iter>=1
//  MODE 2: read fp32 feat only (fallback when ws too small)
// Structure: 4 waves; lane=(g,s); group g owns nodes wv*npw+4*qd+g.
// Pivot softmax (C = first-node logit per group), reconciled at merge.
// grid: 2048 blocks (0..1023 bonds, 1024..2047 atoms), 256 threads.
// ---------------------------------------------------------------------------
template <int MODE>
__global__ __launch_bounds__(256) void k_attn(
    const float* __restrict__ featA, const float* __restrict__ featB,
    unsigned short* __restrict__ fbfA, unsigned short* __restrict__ fbfB,
    const float* __restrict__ gates, const float* __restrict__ bsum,
    float* __restrict__ hr, float* __restrict__ cst, int iter)
{
    __shared__ float qv[256];
    __shared__ float sw_s[16], cw_s[16];
    __shared__ float racc_s[16][260];

    int bid = blockIdx.x;
    int set = (bid < 1024) ? 1 : 0;          // bonds first (2x work)
    int b   = bid & 1023;
    int K   = set ? KBOND : KATOM;
    int t = threadIdx.x;
    size_t sb = (size_t)(set << 10) + b;

    // ---- stage 1: LSTM elementwise, d = t ----
    {
        int d = t;
        float gi, gf, gg, go, cold;
        if (iter == 0) {
            gi = bsum[(set << 10) + d];
            gf = bsum[(set << 10) + 256 + d];
            gg = bsum[(set << 10) + 512 + d];
            go = bsum[(set << 10) + 768 + d];
            cold = 0.0f;
        } else {
            const float* g = gates + sb * 1024;
            gi = g[d]; gf = g[256 + d]; gg = g[512 + d]; go = g[768 + d];
            cold = cst[sb * 256 + d];
        }
        float cn = sigm(gf) * cold + sigm(gi) * tanh_f(gg);
        float h  = sigm(go) * tanh_f(cn);
        cst[sb * 256 + d]  = cn;
        hr[sb * 512 + d]   = h;
        qv[d] = h;
    }
    __syncthreads();

    int lane = t & 63;
    int wv   = t >> 6;
    int g    = lane >> 4;
    int s    = lane & 15;
    int npw  = K >> 2;        // nodes per wave
    int nq   = npw >> 2;      // quads per wave
    int node0 = wv * npw + g; // first node of this lane's group

    float C = 0.0f, sacc = 0.0f;
    int pid = (wv << 2) | g;

    if (MODE == 1) {
        // ---- bf16 read path: lane owns d = {s*8..+8} and {128+s*8..+8} ----
        const unsigned short* fb = (set ? fbfB : fbfA)
                                 + ((size_t)b * K + node0) * 256 + s * 8;
        float qr[16];
        #pragma unroll
        for (int j = 0; j < 8; ++j) { qr[j] = qv[s*8 + j]; qr[8+j] = qv[128 + s*8 + j]; }

        float r[16];
        #pragma unroll
        for (int j = 0; j < 16; ++j) r[j] = 0.0f;

        #pragma unroll 4
        for (int qd = 0; qd < nq; ++qd) {
            const unsigned short* p = fb + (size_t)qd * 1024;
            upk8_t h0 = *(const upk8_t*)(p);
            upk8_t h1 = *(const upk8_t*)(p + 128);
            float x[16];
            #pragma unroll
            for (int j = 0; j < 8; ++j) { x[j] = bf2f(h0[j]); x[8+j] = bf2f(h1[j]); }
            float e = 0.0f;
            #pragma unroll
            for (int j = 0; j < 16; ++j) e += x[j] * qr[j];
            e += __shfl_xor(e, 1);
            e += __shfl_xor(e, 2);
            e += __shfl_xor(e, 4);
            e += __shfl_xor(e, 8);
            float w = (qd == 0) ? 1.0f : __expf(e - C);
            if (qd == 0) C = e;
            sacc += w;
            #pragma unroll
            for (int j = 0; j < 16; ++j) r[j] += w * x[j];
        }
        #pragma unroll
        for (int j = 0; j < 8; j += 4) {
            *(float4*)&racc_s[pid][s*8 + j]       = *(float4*)&r[j];
            *(float4*)&racc_s[pid][128 + s*8 + j] = *(float4*)&r[8+j];
        }
    } else {
        // ---- fp32 read path: lane owns d = {c*64 + s*4..+4}, c=0..3 ----
        const float* feat = set ? featB : featA;
        const float* fb = feat + ((size_t)b * K + node0) * 256 + s * 4;
        unsigned short* fw = (MODE == 0)
            ? (set ? fbfB : fbfA) + ((size_t)b * K + node0) * 256 + s * 4
            : (unsigned short*)0;

        float4 q0 = *(const float4*)&qv[s*4];
        float4 q1 = *(const float4*)&qv[64  + s*4];
        float4 q2 = *(const float4*)&qv[128 + s*4];
        float4 q3 = *(const float4*)&qv[192 + s*4];

        float4 r0 = make_float4(0.f,0.f,0.f,0.f), r1 = r0, r2 = r0, r3 = r0;

        #pragma unroll 2
        for (int qd = 0; qd < nq; ++qd) {
            const float* p = fb + (size_t)qd * 1024;
            float4 x0 = *(const float4*)(p);
            float4 x1 = *(const float4*)(p + 64);
            float4 x2 = *(const float4*)(p + 128);
            float4 x3 = *(const float4*)(p + 192);
            if (MODE == 0) {
                unsigned short* pw = fw + (size_t)qd * 1024;
                upk4_t u;
                u[0]=f2bf(x0.x); u[1]=f2bf(x0.y); u[2]=f2bf(x0.z); u[3]=f2bf(x0.w);
                *(upk4_t*)(pw)       = u;
                u[0]=f2bf(x1.x); u[1]=f2bf(x1.y); u[2]=f2bf(x1.z); u[3]=f2bf(x1.w);
                *(upk4_t*)(pw + 64)  = u;
                u[0]=f2bf(x2.x); u[1]=f2bf(x2.y); u[2]=f2bf(x2.z); u[3]=f2bf(x2.w);
                *(upk4_t*)(pw + 128) = u;
                u[0]=f2bf(x3.x); u[1]=f2bf(x3.y); u[2]=f2bf(x3.z); u[3]=f2bf(x3.w);
                *(upk4_t*)(pw + 192) = u;
            }
            float e = x0.x*q0.x + x0.y*q0.y + x0.z*q0.z + x0.w*q0.w
                    + x1.x*q1.x + x1.y*q1.y + x1.z*q1.z + x1.w*q1.w
                    + x2.x*q2.x + x2.y*q2.y + x2.z*q2.z + x2.w*q2.w
                    + x3.x*q3.x + x3.y*q3.y + x3.z*q3.z + x3.w*q3.w;
            e += __shfl_xor(e, 1);
            e += __shfl_xor(e, 2);
            e += __shfl_xor(e, 4);
            e += __shfl_xor(e, 8);
            float w = (qd == 0) ? 1.0f : __expf(e - C);
            if (qd == 0) C = e;
            sacc += w;
            r0.x += w*x0.x; r0.y += w*x0.y; r0.z += w*x0.z; r0.w += w*x0.w;
            r1.x += w*x1.x; r1.y += w*x1.y; r1.z += w*x1.z; r1.w += w*x1.w;
            r2.x += w*x2.x; r2.y += w*x2.y; r2.z += w*x2.z; r2.w += w*x2.w;
            r3.x += w*x3.x; r3.y += w*x3.y; r3.z += w*x3.z; r3.w += w*x3.w;
        }
        *(float4*)&racc_s[pid][s*4]       = r0;
        *(float4*)&racc_s[pid][64  + s*4] = r1;
        *(float4*)&racc_s[pid][128 + s*4] = r2;
        *(float4*)&racc_s[pid][192 + s*4] = r3;
    }
    if (s == 0) { sw_s[pid] = sacc; cw_s[pid] = C; }
    __syncthreads();

    // ---- stage 3: pivot-reconciled merge of 16 partials, d = t ----
    {
        float Cm = cw_s[0];
        #pragma unroll
        for (int p2 = 1; p2 < 16; ++p2) Cm = fmaxf(Cm, cw_s[p2]);
        float S = 0.0f, r = 0.0f;
        #pragma unroll
        for (int p2 = 0; p2 < 16; ++p2) {
            float f = __expf(cw_s[p2] - Cm);
            S += sw_s[p2] * f;
            r += racc_s[p2][t] * f;
        }
        hr[sb * 512 + 256 + t] = r / S;
    }
}

// ---------------------------------------------------------------------------
// Final concat: out[b] = [hr_atom[b] (512) | hr_bond[b] (512) | fg[b] (128)]
// ---------------------------------------------------------------------------
__global__ __launch_bounds__(288) void k_out(
    const float* __restrict__ hr, const float* __restrict__ fg,
    float* __restrict__ out)
{
    int b  = blockIdx.x;
    int c4 = threadIdx.x * 4;
    float4 v;
    if (c4 < 512)       v = *(const float4*)&hr[(size_t)b * 512 + c4];
    else if (c4 < 1024) v = *(const float4*)&hr[(size_t)(1024 + b) * 512 + (c4 - 512)];
    else                v = *(const float4*)&fg[(size_t)b * 128 + (c4 - 1024)];
    *(float4*)&out[(size_t)b * 1152 + c4] = v;
}

extern "C" void kernel_launch(void* const* d_in, const int* in_sizes, int n_in,
                              void* d_out, int out_size, void* d_ws, size_t ws_size,
                              hipStream_t stream) {
    const float* feat_atom   = (const float*)d_in[0];
    const float* feat_bond   = (const float*)d_in[2];
    const float* feat_global = (const float*)d_in[4];
    const float* WihA = (const float*)d_in[5];
    const float* WhhA = (const float*)d_in[6];
    const float* bihA = (const float*)d_in[7];
    const float* bhhA = (const float*)d_in[8];
    const float* WihB = (const float*)d_in[9];
    const float* WhhB = (const float*)d_in[10];
    const float* bihB = (const float*)d_in[11];
    const float* bhhB = (const float*)d_in[12];
    float* out = (float*)d_out;

    // workspace layout (bytes)
    char* ws = (char*)d_ws;
    unsigned short* Wc = (unsigned short*)(ws + 0);           // 2,097,152
    float* bsum  = (float*)(ws + 2097152);                    // 8,192
    float* gates = (float*)(ws + 2105344);                    // 8,388,608
    float* hr    = (float*)(ws + 10493952);                   // 4,194,304
    float* cst   = (float*)(ws + 14688256);                   // 2,097,152
    unsigned short* fbfA = (unsigned short*)(ws + 16785408);  // 65536*256*2  = 33,554,432
    unsigned short* fbfB = (unsigned short*)(ws + 50339840);  // 131072*256*2 = 67,108,864
    const size_t WS_NEED = 50339840 + 67108864;               // 117,448,704
    (void)in_sizes; (void)n_in; (void)out_size;

    bool bf = (ws_size >= WS_NEED);

    k_prep<<<2048, 512, 0, stream>>>(WihA, WhhA, bihA, bhhA,
                                     WihB, WhhB, bihB, bhhB, Wc, bsum);
    if (bf) {
        k_attn<0><<<2048, 256, 0, stream>>>(feat_atom, feat_bond, fbfA, fbfB,
                                            gates, bsum, hr, cst, 0);
        for (int it = 1; it < 6; ++it) {
            k_gemm<<<128, 256, 0, stream>>>(hr, Wc, bsum, gates);
            k_attn<1><<<2048, 256, 0, stream>>>(feat_atom, feat_bond, fbfA, fbfB,
                                                gates, bsum, hr, cst, it);
        }
    } else {
        k_attn<2><<<2048, 256, 0, stream>>>(feat_atom, feat_bond, 0, 0,
                                            gates, bsum, hr, cst, 0);
        for (int it = 1; it < 6; ++it) {
            k_gemm<<<128, 256, 0, stream>>>(hr, Wc, bsum, gates);
            k_attn<2><<<2048, 256, 0, stream>>>(feat_atom, feat_bond, 0, 0,
                                                gates, bsum, hr, cst, it);
        }
    }
    k_out<<<1024, 288, 0, stream>>>(hr, feat_global, out);
}

// Round 5
// 260.548 us; speedup vs baseline: 1.8459x; 1.0309x over previous
//
#include <hip/hip_runtime.h>
#include <stdint.h>

// Problem constants (from reference)
#define NGRAPH 1024
#define DFEAT  256     // D
#define KATOM  64      // atoms per graph
#define KBOND  128     // bonds per graph

typedef __attribute__((ext_vector_type(4))) float accv_t;     // MFMA C/D (4 fp32)
typedef __attribute__((ext_vector_type(8))) short bfrag_t;    // MFMA A/B (8 bf16)
typedef __attribute__((ext_vector_type(4))) unsigned short upk4_t;
typedef __attribute__((ext_vector_type(8))) unsigned short upk8_t;

__device__ __forceinline__ unsigned short f2bf(float f) {
    union { float f; unsigned int u; } v; v.f = f;
    unsigned int r = (v.u + 0x7FFFu + ((v.u >> 16) & 1u)) >> 16;
    return (unsigned short)r;
}
__device__ __forceinline__ float bf2f(unsigned short h) {
    union { unsigned int u; float f; } v; v.u = ((unsigned int)h) << 16;
    return v.f;
}
__device__ __forceinline__ float sigm(float x) { return 1.0f / (1.0f + __expf(-x)); }
__device__ __forceinline__ float tanh_f(float x) {
    float e = __expf(2.0f * x);
    return 1.0f - 2.0f / (e + 1.0f);
}

// ---------------------------------------------------------------------------
// Streaming fp32 -> bf16 conversion of both feature arrays. Pure grid-stride,
// no cross-lane deps => pipelines to copy BW. Non-temporal loads keep the
// (never-again-read) fp32 data out of L3 so the bf16 copy stays resident.
// grid: 2048 x 256. atom: 4,194,304 float4 (8/thread); bond: 8,388,608 (16).
// ---------------------------------------------------------------------------
__global__ __launch_bounds__(256) void k_cvt(
    const float* __restrict__ fA, const float* __restrict__ fB,
    unsigned short* __restrict__ oA, unsigned short* __restrict__ oB)
{
    int tid = blockIdx.x * 256 + threadIdx.x;
    const int T = 2048 * 256;
    #pragma unroll 2
    for (int i = tid; i < 4194304; i += T) {
        accv_t v = __builtin_nontemporal_load((const accv_t*)fA + i);
        upk4_t u;
        u[0] = f2bf(v[0]); u[1] = f2bf(v[1]); u[2] = f2bf(v[2]); u[3] = f2bf(v[3]);
        *((upk4_t*)oA + i) = u;
    }
    #pragma unroll 2
    for (int i = tid; i < 8388608; i += T) {
        accv_t v = __builtin_nontemporal_load((const accv_t*)fB + i);
        upk4_t u;
        u[0] = f2bf(v[0]); u[1] = f2bf(v[1]); u[2] = f2bf(v[2]); u[3] = f2bf(v[3]);
        *((upk4_t*)oB + i) = u;
    }
}

// ---------------------------------------------------------------------------
// Prep: Wc[set][n][k] (bf16), k<256: W_ih[n,k]+W_hh[n,k]; k>=256: W_ih[n,k].
// ---------------------------------------------------------------------------
__global__ __launch_bounds__(512) void k_prep(
    const float* __restrict__ WihA, const float* __restrict__ WhhA,
    const float* __restrict__ bihA, const float* __restrict__ bhhA,
    const float* __restrict__ WihB, const float* __restrict__ WhhB,
    const float* __restrict__ bihB, const float* __restrict__ bhhB,
    unsigned short* __restrict__ Wc, float* __restrict__ bsum)
{
    int bid = blockIdx.x;
    int set = bid >> 10;
    int n   = bid & 1023;
    int k   = threadIdx.x;
    const float* Wih = set ? WihB : WihA;
    const float* Whh = set ? WhhB : WhhA;
    float w = Wih[(size_t)n * 512 + k];
    if (k < 256) w += Whh[(size_t)n * 256 + k];
    Wc[((size_t)(set << 10) + n) * 512 + k] = f2bf(w);
    if (k == 0) {
        const float* bih = set ? bihB : bihA;
        const float* bhh = set ? bhhB : bhhA;
        bsum[(set << 10) + n] = bih[n] + bhh[n];
    }
}

// ---------------------------------------------------------------------------
// LSTM gate GEMM: M=1024, N=1024, K=512 per set. BM=64, BN=128, BK=32,
// 4 waves (32x64 each), 16x16x32 bf16 MFMA. grid: 256 blocks (set = bid>>7)
// -> every CU gets a block (was 128 blocks = half the CUs idle).
// ---------------------------------------------------------------------------
__global__ __launch_bounds__(256) void k_gemm(
    const float* __restrict__ hr, const unsigned short* __restrict__ Wc,
    const float* __restrict__ bsum, float* __restrict__ gates)
{
    __shared__ unsigned short sA[64 * 40];
    __shared__ unsigned short sB[128 * 40];

    int set   = blockIdx.x >> 7;
    int qq    = blockIdx.x & 127;
    int mbase = (qq >> 3) * 64;
    int nbase = (qq & 7) * 128;
    int t     = threadIdx.x;
    int lane  = t & 63;
    int w     = t >> 6;
    int wrow  = (w >> 1) * 32;
    int wcol  = (w & 1) * 64;
    int l15   = lane & 15;
    int khalf = (lane >> 4) * 8;

    const float* A           = hr + (size_t)(set << 10) * 512;
    const unsigned short* Bm = Wc + (size_t)(set << 10) * 512;

    accv_t acc[2][4];
    #pragma unroll
    for (int i = 0; i < 2; ++i)
        #pragma unroll
        for (int j = 0; j < 4; ++j)
            acc[i][j] = (accv_t){0.f, 0.f, 0.f, 0.f};

    for (int k0 = 0; k0 < 512; k0 += 32) {
        // stage A tile 64x32 (fp32 -> bf16): 512 float4, 2/thread
        #pragma unroll
        for (int i = 0; i < 2; ++i) {
            int idx4 = t + 256 * i;
            int row  = idx4 >> 3;
            int kc   = (idx4 & 7) * 4;
            const float4 a = *(const float4*)&A[(size_t)(mbase + row) * 512 + k0 + kc];
            upk4_t u;
            u[0] = f2bf(a.x); u[1] = f2bf(a.y); u[2] = f2bf(a.z); u[3] = f2bf(a.w);
            *(upk4_t*)&sA[row * 40 + kc] = u;
        }
        // stage B tile 128x32 (bf16 direct): 512 ushort8, 2/thread
        #pragma unroll
        for (int i = 0; i < 2; ++i) {
            int idx8 = t + 256 * i;
            int row  = idx8 >> 2;
            int kc   = (idx8 & 3) * 8;
            upk8_t u = *(const upk8_t*)&Bm[(size_t)(nbase + row) * 512 + k0 + kc];
            *(upk8_t*)&sB[row * 40 + kc] = u;
        }
        __syncthreads();

        bfrag_t a_f[2], b_f[4];
        #pragma unroll
        for (int i = 0; i < 2; ++i)
            a_f[i] = *(const bfrag_t*)&sA[(wrow + i * 16 + l15) * 40 + khalf];
        #pragma unroll
        for (int j = 0; j < 4; ++j)
            b_f[j] = *(const bfrag_t*)&sB[(wcol + j * 16 + l15) * 40 + khalf];
        #pragma unroll
        for (int i = 0; i < 2; ++i)
            #pragma unroll
            for (int j = 0; j < 4; ++j)
                acc[i][j] = __builtin_amdgcn_mfma_f32_16x16x32_bf16(a_f[i], b_f[j], acc[i][j], 0, 0, 0);
        __syncthreads();
    }

    int r4 = (lane >> 4) * 4;
    #pragma unroll
    for (int i = 0; i < 2; ++i) {
        #pragma unroll
        for (int j = 0; j < 4; ++j) {
            int col  = nbase + wcol + j * 16 + l15;
            float bs = bsum[(set << 10) + col];
            #pragma unroll
            for (int v = 0; v < 4; ++v) {
                int row = mbase + wrow + i * 16 + r4 + v;
                gates[((size_t)(set << 10) + row) * 1024 + col] = acc[i][j][v] + bs;
            }
        }
    }
}

// ---------------------------------------------------------------------------
// Attention, templated on MODE:
//  MODE 1: read bf16 copy (all 6 iterations)
//  MODE 2: read fp32 feat (fallback when ws too small)
// Structure: 4 waves; lane=(g,s); group g owns nodes wv*npw+4*qd+g.
// Pivot softmax (C = first-node logit per group), reconciled at merge.
// grid: 2048 blocks (0..1023 bonds, 1024..2047 atoms), 256 threads.
// ---------------------------------------------------------------------------
template <int MODE>
__global__ __launch_bounds__(256) void k_attn(
    const float* __restrict__ featA, const float* __restrict__ featB,
    const unsigned short* __restrict__ fbfA, const unsigned short* __restrict__ fbfB,
    const float* __restrict__ gates, const float* __restrict__ bsum,
    float* __restrict__ hr, float* __restrict__ cst, int iter)
{
    __shared__ float qv[256];
    __shared__ float sw_s[16], cw_s[16];
    __shared__ float racc_s[16][260];

    int bid = blockIdx.x;
    int set = (bid < 1024) ? 1 : 0;          // bonds first (2x work)
    int b   = bid & 1023;
    int K   = set ? KBOND : KATOM;
    int t = threadIdx.x;
    size_t sb = (size_t)(set << 10) + b;

    // ---- stage 1: LSTM elementwise, d = t ----
    {
        int d = t;
        float gi, gf, gg, go, cold;
        if (iter == 0) {
            gi = bsum[(set << 10) + d];
            gf = bsum[(set << 10) + 256 + d];
            gg = bsum[(set << 10) + 512 + d];
            go = bsum[(set << 10) + 768 + d];
            cold = 0.0f;
        } else {
            const float* g = gates + sb * 1024;
            gi = g[d]; gf = g[256 + d]; gg = g[512 + d]; go = g[768 + d];
            cold = cst[sb * 256 + d];
        }
        float cn = sigm(gf) * cold + sigm(gi) * tanh_f(gg);
        float h  = sigm(go) * tanh_f(cn);
        cst[sb * 256 + d]  = cn;
        hr[sb * 512 + d]   = h;
        qv[d] = h;
    }
    __syncthreads();

    int lane = t & 63;
    int wv   = t >> 6;
    int g    = lane >> 4;
    int s    = lane & 15;
    int npw  = K >> 2;
    int nq   = npw >> 2;
    int node0 = wv * npw + g;

    float C = 0.0f, sacc = 0.0f;
    int pid = (wv << 2) | g;

    if (MODE == 1) {
        // ---- bf16 read path: lane owns d = {s*8..+8} and {128+s*8..+8} ----
        const unsigned short* fb = (set ? fbfB : fbfA)
                                 + ((size_t)b * K + node0) * 256 + s * 8;
        float qr[16];
        #pragma unroll
        for (int j = 0; j < 8; ++j) { qr[j] = qv[s*8 + j]; qr[8+j] = qv[128 + s*8 + j]; }

        float r[16];
        #pragma unroll
        for (int j = 0; j < 16; ++j) r[j] = 0.0f;

        #pragma unroll 4
        for (int qd = 0; qd < nq; ++qd) {
            const unsigned short* p = fb + (size_t)qd * 1024;
            upk8_t h0 = *(const upk8_t*)(p);
            upk8_t h1 = *(const upk8_t*)(p + 128);
            float x[16];
            #pragma unroll
            for (int j = 0; j < 8; ++j) { x[j] = bf2f(h0[j]); x[8+j] = bf2f(h1[j]); }
            float e = 0.0f;
            #pragma unroll
            for (int j = 0; j < 16; ++j) e += x[j] * qr[j];
            e += __shfl_xor(e, 1);
            e += __shfl_xor(e, 2);
            e += __shfl_xor(e, 4);
            e += __shfl_xor(e, 8);
            float w = (qd == 0) ? 1.0f : __expf(e - C);
            if (qd == 0) C = e;
            sacc += w;
            #pragma unroll
            for (int j = 0; j < 16; ++j) r[j] += w * x[j];
        }
        #pragma unroll
        for (int j = 0; j < 8; j += 4) {
            *(float4*)&racc_s[pid][s*8 + j]       = *(float4*)&r[j];
            *(float4*)&racc_s[pid][128 + s*8 + j] = *(float4*)&r[8+j];
        }
    } else {
        // ---- fp32 fallback path: lane owns d = {c*64 + s*4..+4}, c=0..3 ----
        const float* feat = set ? featB : featA;
        const float* fb = feat + ((size_t)b * K + node0) * 256 + s * 4;

        float4 q0 = *(const float4*)&qv[s*4];
        float4 q1 = *(const float4*)&qv[64  + s*4];
        float4 q2 = *(const float4*)&qv[128 + s*4];
        float4 q3 = *(const float4*)&qv[192 + s*4];

        float4 r0 = make_float4(0.f,0.f,0.f,0.f), r1 = r0, r2 = r0, r3 = r0;

        #pragma unroll 2
        for (int qd = 0; qd < nq; ++qd) {
            const float* p = fb + (size_t)qd * 1024;
            float4 x0 = *(const float4*)(p);
            float4 x1 = *(const float4*)(p + 64);
            float4 x2 = *(const float4*)(p + 128);
            float4 x3 = *(const float4*)(p + 192);
            float e = x0.x*q0.x + x0.y*q0.y + x0.z*q0.z + x0.w*q0.w
                    + x1.x*q1.x + x1.y*q1.y + x1.z*q1.z + x1.w*q1.w
                    + x2.x*q2.x + x2.y*q2.y + x2.z*q2.z + x2.w*q2.w
                    + x3.x*q3.x + x3.y*q3.y + x3.z*q3.z + x3.w*q3.w;
            e += __shfl_xor(e, 1);
            e += __shfl_xor(e, 2);
            e += __shfl_xor(e, 4);
            e += __shfl_xor(e, 8);
            float w = (qd == 0) ? 1.0f : __expf(e - C);
            if (qd == 0) C = e;
            sacc += w;
            r0.x += w*x0.x; r0.y += w*x0.y; r0.z += w*x0.z; r0.w += w*x0.w;
            r1.x += w*x1.x; r1.y += w*x1.y; r1.z += w*x1.z; r1.w += w*x1.w;
            r2.x += w*x2.x; r2.y += w*x2.y; r2.z += w*x2.z; r2.w += w*x2.w;
            r3.x += w*x3.x; r3.y += w*x3.y; r3.z += w*x3.z; r3.w += w*x3.w;
        }
        *(float4*)&racc_s[pid][s*4]       = r0;
        *(float4*)&racc_s[pid][64  + s*4] = r1;
        *(float4*)&racc_s[pid][128 + s*4] = r2;
        *(float4*)&racc_s[pid][192 + s*4] = r3;
    }
    if (s == 0) { sw_s[pid] = sacc; cw_s[pid] = C; }
    __syncthreads();

    // ---- stage 3: pivot-reconciled merge of 16 partials, d = t ----
    {
        float Cm = cw_s[0];
        #pragma unroll
        for (int p2 = 1; p2 < 16; ++p2) Cm = fmaxf(Cm, cw_s[p2]);
        float S = 0.0f, r = 0.0f;
        #pragma unroll
        for (int p2 = 0; p2 < 16; ++p2) {
            float f = __expf(cw_s[p2] - Cm);
            S += sw_s[p2] * f;
            r += racc_s[p2][t] * f;
        }
        hr[sb * 512 + 256 + t] = r / S;
    }
}

// ---------------------------------------------------------------------------
// Final concat: out[b] = [hr_atom[b] (512) | hr_bond[b] (512) | fg[b] (128)]
// ---------------------------------------------------------------------------
__global__ __launch_bounds__(288) void k_out(
    const float* __restrict__ hr, const float* __restrict__ fg,
    float* __restrict__ out)
{
    int b  = blockIdx.x;
    int c4 = threadIdx.x * 4;
    float4 v;
    if (c4 < 512)       v = *(const float4*)&hr[(size_t)b * 512 + c4];
    else if (c4 < 1024) v = *(const float4*)&hr[(size_t)(1024 + b) * 512 + (c4 - 512)];
    else                v = *(const float4*)&fg[(size_t)b * 128 + (c4 - 1024)];
    *(float4*)&out[(size_t)b * 1152 + c4] = v;
}

extern "C" void kernel_launch(void* const* d_in, const int* in_sizes, int n_in,
                              void* d_out, int out_size, void* d_ws, size_t ws_size,
                              hipStream_t stream) {
    const float* feat_atom   = (const float*)d_in[0];
    const float* feat_bond   = (const float*)d_in[2];
    const float* feat_global = (const float*)d_in[4];
    const float* WihA = (const float*)d_in[5];
    const float* WhhA = (const float*)d_in[6];
    const float* bihA = (const float*)d_in[7];
    const float* bhhA = (const float*)d_in[8];
    const float* WihB = (const float*)d_in[9];
    const float* WhhB = (const float*)d_in[10];
    const float* bihB = (const float*)d_in[11];
    const float* bhhB = (const float*)d_in[12];
    float* out = (float*)d_out;

    // workspace layout (bytes)
    char* ws = (char*)d_ws;
    unsigned short* Wc = (unsigned short*)(ws + 0);           // 2,097,152
    float* bsum  = (float*)(ws + 2097152);                    // 8,192
    float* gates = (float*)(ws + 2105344);                    // 8,388,608
    float* hr    = (float*)(ws + 10493952);                   // 4,194,304
    float* cst   = (float*)(ws + 14688256);                   // 2,097,152
    unsigned short* fbfA = (unsigned short*)(ws + 16785408);  // 33,554,432
    unsigned short* fbfB = (unsigned short*)(ws + 50339840);  // 67,108,864
    const size_t WS_NEED = 50339840 + 67108864;               // 117,448,704
    (void)in_sizes; (void)n_in; (void)out_size;

    bool bf = (ws_size >= WS_NEED);

    k_prep<<<2048, 512, 0, stream>>>(WihA, WhhA, bihA, bhhA,
                                     WihB, WhhB, bihB, bhhB, Wc, bsum);
    if (bf) {
        k_cvt<<<2048, 256, 0, stream>>>(feat_atom, feat_bond, fbfA, fbfB);
        k_attn<1><<<2048, 256, 0, stream>>>(feat_atom, feat_bond, fbfA, fbfB,
                                            gates, bsum, hr, cst, 0);
        for (int it = 1; it < 6; ++it) {
            k_gemm<<<256, 256, 0, stream>>>(hr, Wc, bsum, gates);
            k_attn<1><<<2048, 256, 0, stream>>>(feat_atom, feat_bond, fbfA, fbfB,
                                                gates, bsum, hr, cst, it);
        }
    } else {
        k_attn<2><<<2048, 256, 0, stream>>>(feat_atom, feat_bond, 0, 0,
                                            gates, bsum, hr, cst, 0);
        for (int it = 1; it < 6; ++it) {
            k_gemm<<<256, 256, 0, stream>>>(hr, Wc, bsum, gates);
            k_attn<2><<<2048, 256, 0, stream>>>(feat_atom, feat_bond, 0, 0,
                                                gates, bsum, hr, cst, it);
        }
    }
    k_out<<<1024, 288, 0, stream>>>(hr, feat_global, out);
}

// Round 6
// 260.500 us; speedup vs baseline: 1.8462x; 1.0002x over previous
//
#include <hip/hip_runtime.h>
#include <stdint.h>

// Problem constants (from reference)
#define NGRAPH 1024
#define DFEAT  256     // D
#define KATOM  64      // atoms per graph
#define KBOND  128     // bonds per graph

typedef __attribute__((ext_vector_type(4))) float accv_t;     // MFMA C/D (4 fp32)
typedef __attribute__((ext_vector_type(8))) short bfrag_t;    // MFMA A/B (8 bf16)
typedef __attribute__((ext_vector_type(4))) unsigned short upk4_t;
typedef __attribute__((ext_vector_type(8))) unsigned short upk8_t;

__device__ __forceinline__ unsigned short f2bf(float f) {
    union { float f; unsigned int u; } v; v.f = f;
    unsigned int r = (v.u + 0x7FFFu + ((v.u >> 16) & 1u)) >> 16;
    return (unsigned short)r;
}
__device__ __forceinline__ float bf2f(unsigned short h) {
    union { unsigned int u; float f; } v; v.u = ((unsigned int)h) << 16;
    return v.f;
}
__device__ __forceinline__ float sigm(float x) { return 1.0f / (1.0f + __expf(-x)); }
__device__ __forceinline__ float tanh_f(float x) {
    float e = __expf(2.0f * x);
    return 1.0f - 2.0f / (e + 1.0f);
}

// ---------------------------------------------------------------------------
// Streaming fp32 -> bf16 conversion of both feature arrays. Non-temporal
// loads keep the never-again-read fp32 data out of L3.
// ---------------------------------------------------------------------------
__global__ __launch_bounds__(256) void k_cvt(
    const float* __restrict__ fA, const float* __restrict__ fB,
    unsigned short* __restrict__ oA, unsigned short* __restrict__ oB)
{
    int tid = blockIdx.x * 256 + threadIdx.x;
    const int T = 2048 * 256;
    #pragma unroll 2
    for (int i = tid; i < 4194304; i += T) {
        accv_t v = __builtin_nontemporal_load((const accv_t*)fA + i);
        upk4_t u;
        u[0] = f2bf(v[0]); u[1] = f2bf(v[1]); u[2] = f2bf(v[2]); u[3] = f2bf(v[3]);
        *((upk4_t*)oA + i) = u;
    }
    #pragma unroll 2
    for (int i = tid; i < 8388608; i += T) {
        accv_t v = __builtin_nontemporal_load((const accv_t*)fB + i);
        upk4_t u;
        u[0] = f2bf(v[0]); u[1] = f2bf(v[1]); u[2] = f2bf(v[2]); u[3] = f2bf(v[3]);
        *((upk4_t*)oB + i) = u;
    }
}

// ---------------------------------------------------------------------------
// Prep: Wc[set][n][k] (bf16), k<256: W_ih[n,k]+W_hh[n,k]; k>=256: W_ih[n,k].
// ---------------------------------------------------------------------------
__global__ __launch_bounds__(512) void k_prep(
    const float* __restrict__ WihA, const float* __restrict__ WhhA,
    const float* __restrict__ bihA, const float* __restrict__ bhhA,
    const float* __restrict__ WihB, const float* __restrict__ WhhB,
    const float* __restrict__ bihB, const float* __restrict__ bhhB,
    unsigned short* __restrict__ Wc, float* __restrict__ bsum)
{
    int bid = blockIdx.x;
    int set = bid >> 10;
    int n   = bid & 1023;
    int k   = threadIdx.x;
    const float* Wih = set ? WihB : WihA;
    const float* Whh = set ? WhhB : WhhA;
    float w = Wih[(size_t)n * 512 + k];
    if (k < 256) w += Whh[(size_t)n * 256 + k];
    Wc[((size_t)(set << 10) + n) * 512 + k] = f2bf(w);
    if (k == 0) {
        const float* bih = set ? bihB : bihA;
        const float* bhh = set ? bhhB : bhhA;
        bsum[(set << 10) + n] = bih[n] + bhh[n];
    }
}

// ---------------------------------------------------------------------------
// LSTM gate GEMM: M=1024, N=1024, K=512 per set. BM=64, BN=128, BK=32,
// 4 waves (32x64 each), 16x16x32 bf16 MFMA. grid: 256 blocks (set = bid>>7).
// ---------------------------------------------------------------------------
__global__ __launch_bounds__(256) void k_gemm(
    const float* __restrict__ hr, const unsigned short* __restrict__ Wc,
    const float* __restrict__ bsum, float* __restrict__ gates)
{
    __shared__ unsigned short sA[64 * 40];
    __shared__ unsigned short sB[128 * 40];

    int set   = blockIdx.x >> 7;
    int qq    = blockIdx.x & 127;
    int mbase = (qq >> 3) * 64;
    int nbase = (qq & 7) * 128;
    int t     = threadIdx.x;
    int lane  = t & 63;
    int w     = t >> 6;
    int wrow  = (w >> 1) * 32;
    int wcol  = (w & 1) * 64;
    int l15   = lane & 15;
    int khalf = (lane >> 4) * 8;

    const float* A           = hr + (size_t)(set << 10) * 512;
    const unsigned short* Bm = Wc + (size_t)(set << 10) * 512;

    accv_t acc[2][4];
    #pragma unroll
    for (int i = 0; i < 2; ++i)
        #pragma unroll
        for (int j = 0; j < 4; ++j)
            acc[i][j] = (accv_t){0.f, 0.f, 0.f, 0.f};

    for (int k0 = 0; k0 < 512; k0 += 32) {
        #pragma unroll
        for (int i = 0; i < 2; ++i) {
            int idx4 = t + 256 * i;
            int row  = idx4 >> 3;
            int kc   = (idx4 & 7) * 4;
            const float4 a = *(const float4*)&A[(size_t)(mbase + row) * 512 + k0 + kc];
            upk4_t u;
            u[0] = f2bf(a.x); u[1] = f2bf(a.y); u[2] = f2bf(a.z); u[3] = f2bf(a.w);
            *(upk4_t*)&sA[row * 40 + kc] = u;
        }
        #pragma unroll
        for (int i = 0; i < 2; ++i) {
            int idx8 = t + 256 * i;
            int row  = idx8 >> 2;
            int kc   = (idx8 & 3) * 8;
            upk8_t u = *(const upk8_t*)&Bm[(size_t)(nbase + row) * 512 + k0 + kc];
            *(upk8_t*)&sB[row * 40 + kc] = u;
        }
        __syncthreads();

        bfrag_t a_f[2], b_f[4];
        #pragma unroll
        for (int i = 0; i < 2; ++i)
            a_f[i] = *(const bfrag_t*)&sA[(wrow + i * 16 + l15) * 40 + khalf];
        #pragma unroll
        for (int j = 0; j < 4; ++j)
            b_f[j] = *(const bfrag_t*)&sB[(wcol + j * 16 + l15) * 40 + khalf];
        #pragma unroll
        for (int i = 0; i < 2; ++i)
            #pragma unroll
            for (int j = 0; j < 4; ++j)
                acc[i][j] = __builtin_amdgcn_mfma_f32_16x16x32_bf16(a_f[i], b_f[j], acc[i][j], 0, 0, 0);
        __syncthreads();
    }

    int r4 = (lane >> 4) * 4;
    #pragma unroll
    for (int i = 0; i < 2; ++i) {
        #pragma unroll
        for (int j = 0; j < 4; ++j) {
            int col  = nbase + wcol + j * 16 + l15;
            float bs = bsum[(set << 10) + col];
            #pragma unroll
            for (int v = 0; v < 4; ++v) {
                int row = mbase + wrow + i * 16 + r4 + v;
                gates[((size_t)(set << 10) + row) * 1024 + col] = acc[i][j][v] + bs;
            }
        }
    }
}

// ---------------------------------------------------------------------------
// Attention core (bf16 path): ALL 2*NQ loads hoisted before any compute so
// the wave has 16 (bond) / 8 (atom) loads in flight -> latency amortized.
// ---------------------------------------------------------------------------
template <int NQ>
__device__ __forceinline__ void attn_core(
    const unsigned short* __restrict__ fb, const float* __restrict__ qv,
    int s, float* __restrict__ rrow, float& C, float& sacc)
{
    upk8_t h0[NQ], h1[NQ];
    #pragma unroll
    for (int qd = 0; qd < NQ; ++qd) {
        const unsigned short* p = fb + (size_t)qd * 1024;
        h0[qd] = *(const upk8_t*)(p);
        h1[qd] = *(const upk8_t*)(p + 128);
    }
    float qr[16];
    #pragma unroll
    for (int j = 0; j < 8; ++j) { qr[j] = qv[s*8 + j]; qr[8+j] = qv[128 + s*8 + j]; }

    float r[16];
    #pragma unroll
    for (int j = 0; j < 16; ++j) r[j] = 0.0f;

    #pragma unroll
    for (int qd = 0; qd < NQ; ++qd) {
        float x[16];
        #pragma unroll
        for (int j = 0; j < 8; ++j) { x[j] = bf2f(h0[qd][j]); x[8+j] = bf2f(h1[qd][j]); }
        float e = 0.0f;
        #pragma unroll
        for (int j = 0; j < 16; ++j) e += x[j] * qr[j];
        e += __shfl_xor(e, 1);
        e += __shfl_xor(e, 2);
        e += __shfl_xor(e, 4);
        e += __shfl_xor(e, 8);
        float w = (qd == 0) ? 1.0f : __expf(e - C);
        if (qd == 0) C = e;
        sacc += w;
        #pragma unroll
        for (int j = 0; j < 16; ++j) r[j] += w * x[j];
    }
    #pragma unroll
    for (int j = 0; j < 8; j += 4) {
        *(float4*)&rrow[s*8 + j]       = *(float4*)&r[j];
        *(float4*)&rrow[128 + s*8 + j] = *(float4*)&r[8+j];
    }
}

// ---------------------------------------------------------------------------
// Attention, templated on MODE / LAST:
//  MODE 1: read bf16 copy; MODE 2: fp32 fallback.
//  LAST: write q_star (and feat_global tail) straight to out, skip hr/cst.
// grid: 2048 blocks (0..1023 bonds, 1024..2047 atoms), 256 threads.
// ---------------------------------------------------------------------------
template <int MODE, bool LAST>
__global__ __launch_bounds__(256) void k_attn(
    const float* __restrict__ featA, const float* __restrict__ featB,
    const unsigned short* __restrict__ fbfA, const unsigned short* __restrict__ fbfB,
    const float* __restrict__ gates, const float* __restrict__ bsum,
    float* __restrict__ hr, float* __restrict__ cst,
    const float* __restrict__ fg, float* __restrict__ outp, int iter)
{
    __shared__ float qv[256];
    __shared__ float sw_s[16], cw_s[16];
    __shared__ float racc_s[16][260];

    int bid = blockIdx.x;
    int set = (bid < 1024) ? 1 : 0;          // bonds first (2x work)
    int b   = bid & 1023;
    int K   = set ? KBOND : KATOM;
    int t = threadIdx.x;
    size_t sb = (size_t)(set << 10) + b;
    size_t ob = (size_t)b * 1152 + (set ? 512 : 0);   // out base for q_star slice

    // ---- stage 1: LSTM elementwise, d = t ----
    {
        int d = t;
        float gi, gf, gg, go, cold;
        if (iter == 0) {
            gi = bsum[(set << 10) + d];
            gf = bsum[(set << 10) + 256 + d];
            gg = bsum[(set << 10) + 512 + d];
            go = bsum[(set << 10) + 768 + d];
            cold = 0.0f;
        } else {
            const float* g = gates + sb * 1024;
            gi = g[d]; gf = g[256 + d]; gg = g[512 + d]; go = g[768 + d];
            cold = cst[sb * 256 + d];
        }
        float cn = sigm(gf) * cold + sigm(gi) * tanh_f(gg);
        float h  = sigm(go) * tanh_f(cn);
        if (LAST) {
            outp[ob + d] = h;                 // q half straight to out
        } else {
            cst[sb * 256 + d] = cn;
            hr[sb * 512 + d]  = h;
        }
        qv[d] = h;
    }
    __syncthreads();

    int lane = t & 63;
    int wv   = t >> 6;
    int g    = lane >> 4;
    int s    = lane & 15;
    int npw  = K >> 2;
    int nq   = npw >> 2;
    int node0 = wv * npw + g;

    float C = 0.0f, sacc = 0.0f;
    int pid = (wv << 2) | g;

    if (MODE == 1) {
        const unsigned short* fb = (set ? fbfB : fbfA)
                                 + ((size_t)b * K + node0) * 256 + s * 8;
        if (set) attn_core<8>(fb, qv, s, racc_s[pid], C, sacc);
        else     attn_core<4>(fb, qv, s, racc_s[pid], C, sacc);
    } else {
        // ---- fp32 fallback path ----
        const float* feat = set ? featB : featA;
        const float* fb = feat + ((size_t)b * K + node0) * 256 + s * 4;

        float4 q0 = *(const float4*)&qv[s*4];
        float4 q1 = *(const float4*)&qv[64  + s*4];
        float4 q2 = *(const float4*)&qv[128 + s*4];
        float4 q3 = *(const float4*)&qv[192 + s*4];

        float4 r0 = make_float4(0.f,0.f,0.f,0.f), r1 = r0, r2 = r0, r3 = r0;

        #pragma unroll 2
        for (int qd = 0; qd < nq; ++qd) {
            const float* p = fb + (size_t)qd * 1024;
            float4 x0 = *(const float4*)(p);
            float4 x1 = *(const float4*)(p + 64);
            float4 x2 = *(const float4*)(p + 128);
            float4 x3 = *(const float4*)(p + 192);
            float e = x0.x*q0.x + x0.y*q0.y + x0.z*q0.z + x0.w*q0.w
                    + x1.x*q1.x + x1.y*q1.y + x1.z*q1.z + x1.w*q1.w
                    + x2.x*q2.x + x2.y*q2.y + x2.z*q2.z + x2.w*q2.w
                    + x3.x*q3.x + x3.y*q3.y + x3.z*q3.z + x3.w*q3.w;
            e += __shfl_xor(e, 1);
            e += __shfl_xor(e, 2);
            e += __shfl_xor(e, 4);
            e += __shfl_xor(e, 8);
            float w = (qd == 0) ? 1.0f : __expf(e - C);
            if (qd == 0) C = e;
            sacc += w;
            r0.x += w*x0.x; r0.y += w*x0.y; r0.z += w*x0.z; r0.w += w*x0.w;
            r1.x += w*x1.x; r1.y += w*x1.y; r1.z += w*x1.z; r1.w += w*x1.w;
            r2.x += w*x2.x; r2.y += w*x2.y; r2.z += w*x2.z; r2.w += w*x2.w;
            r3.x += w*x3.x; r3.y += w*x3.y; r3.z += w*x3.z; r3.w += w*x3.w;
        }
        *(float4*)&racc_s[pid][s*4]       = r0;
        *(float4*)&racc_s[pid][64  + s*4] = r1;
        *(float4*)&racc_s[pid][128 + s*4] = r2;
        *(float4*)&racc_s[pid][192 + s*4] = r3;
    }
    if (s == 0) { sw_s[pid] = sacc; cw_s[pid] = C; }
    __syncthreads();

    // ---- stage 3: pivot-reconciled merge of 16 partials, d = t ----
    {
        float Cm = cw_s[0];
        #pragma unroll
        for (int p2 = 1; p2 < 16; ++p2) Cm = fmaxf(Cm, cw_s[p2]);
        float S = 0.0f, r = 0.0f;
        #pragma unroll
        for (int p2 = 0; p2 < 16; ++p2) {
            float f = __expf(cw_s[p2] - Cm);
            S += sw_s[p2] * f;
            r += racc_s[p2][t] * f;
        }
        float rv = r / S;
        if (LAST) {
            outp[ob + 256 + t] = rv;
            if (set && t < 128)               // bond blocks also copy feat_global
                outp[(size_t)b * 1152 + 1024 + t] = fg[(size_t)b * 128 + t];
        } else {
            hr[sb * 512 + 256 + t] = rv;
        }
    }
}

// ---------------------------------------------------------------------------
// Final concat (fallback path only).
// ---------------------------------------------------------------------------
__global__ __launch_bounds__(288) void k_out(
    const float* __restrict__ hr, const float* __restrict__ fg,
    float* __restrict__ out)
{
    int b  = blockIdx.x;
    int c4 = threadIdx.x * 4;
    float4 v;
    if (c4 < 512)       v = *(const float4*)&hr[(size_t)b * 512 + c4];
    else if (c4 < 1024) v = *(const float4*)&hr[(size_t)(1024 + b) * 512 + (c4 - 512)];
    else                v = *(const float4*)&fg[(size_t)b * 128 + (c4 - 1024)];
    *(float4*)&out[(size_t)b * 1152 + c4] = v;
}

extern "C" void kernel_launch(void* const* d_in, const int* in_sizes, int n_in,
                              void* d_out, int out_size, void* d_ws, size_t ws_size,
                              hipStream_t stream) {
    const float* feat_atom   = (const float*)d_in[0];
    const float* feat_bond   = (const float*)d_in[2];
    const float* feat_global = (const float*)d_in[4];
    const float* WihA = (const float*)d_in[5];
    const float* WhhA = (const float*)d_in[6];
    const float* bihA = (const float*)d_in[7];
    const float* bhhA = (const float*)d_in[8];
    const float* WihB = (const float*)d_in[9];
    const float* WhhB = (const float*)d_in[10];
    const float* bihB = (const float*)d_in[11];
    const float* bhhB = (const float*)d_in[12];
    float* out = (float*)d_out;

    // workspace layout (bytes)
    char* ws = (char*)d_ws;
    unsigned short* Wc = (unsigned short*)(ws + 0);           // 2,097,152
    float* bsum  = (float*)(ws + 2097152);                    // 8,192
    float* gates = (float*)(ws + 2105344);                    // 8,388,608
    float* hr    = (float*)(ws + 10493952);                   // 4,194,304
    float* cst   = (float*)(ws + 14688256);                   // 2,097,152
    unsigned short* fbfA = (unsigned short*)(ws + 16785408);  // 33,554,432
    unsigned short* fbfB = (unsigned short*)(ws + 50339840);  // 67,108,864
    const size_t WS_NEED = 50339840 + 67108864;               // 117,448,704
    (void)in_sizes; (void)n_in; (void)out_size;

    bool bf = (ws_size >= WS_NEED);

    k_prep<<<2048, 512, 0, stream>>>(WihA, WhhA, bihA, bhhA,
                                     WihB, WhhB, bihB, bhhB, Wc, bsum);
    if (bf) {
        k_cvt<<<2048, 256, 0, stream>>>(feat_atom, feat_bond, fbfA, fbfB);
        k_attn<1, false><<<2048, 256, 0, stream>>>(feat_atom, feat_bond, fbfA, fbfB,
                                                   gates, bsum, hr, cst,
                                                   feat_global, out, 0);
        for (int it = 1; it < 5; ++it) {
            k_gemm<<<256, 256, 0, stream>>>(hr, Wc, bsum, gates);
            k_attn<1, false><<<2048, 256, 0, stream>>>(feat_atom, feat_bond, fbfA, fbfB,
                                                       gates, bsum, hr, cst,
                                                       feat_global, out, it);
        }
        k_gemm<<<256, 256, 0, stream>>>(hr, Wc, bsum, gates);
        k_attn<1, true><<<2048, 256, 0, stream>>>(feat_atom, feat_bond, fbfA, fbfB,
                                                  gates, bsum, hr, cst,
                                                  feat_global, out, 5);
    } else {
        k_attn<2, false><<<2048, 256, 0, stream>>>(feat_atom, feat_bond, 0, 0,
                                                   gates, bsum, hr, cst,
                                                   feat_global, out, 0);
        for (int it = 1; it < 6; ++it) {
            k_gemm<<<256, 256, 0, stream>>>(hr, Wc, bsum, gates);
            k_attn<2, false><<<2048, 256, 0, stream>>>(feat_atom, feat_bond, 0, 0,
                                                       gates, bsum, hr, cst,
                                                       feat_global, out, it);
        }
        k_out<<<1024, 288, 0, stream>>>(hr, feat_global, out);
    }
}